// Round 3
// baseline (370.441 us; speedup 1.0000x reference)
//
#include <hip/hip_runtime.h>

#define GDIM 128
#define NS   128
#define VD   28

// thread = (sample, corner-pair):  tid = 4*s + p,  p in lane quad.
// Each thread gathers 2 corners (z0,z1) = 14 independent float4 loads.
// Quad shfl_xor reduces the 4 corner-pair partials; cumsum = quad-level
// in-wave scan + 8-entry LDS carry. No bulk LDS staging.
__global__ __launch_bounds__(512, 4) void plenoxel_kernel(
    const float* __restrict__ grid,
    const float* __restrict__ pos,
    const float* __restrict__ dist,
    const float* __restrict__ ang,
    float* __restrict__ out)
{
    const int r    = blockIdx.x;
    const int tid  = threadIdx.x;        // 0..511
    const int s    = tid >> 2;           // sample 0..127
    const int p    = tid & 3;            // corner-pair 0..3
    const int dx   = p >> 1;
    const int dy   = p & 1;
    const int lane = tid & 63;
    const int wv   = tid >> 6;           // wave 0..7 (16 samples each)

    // ---- SH basis ----
    const float th = ang[2 * r + 0];
    const float ph = ang[2 * r + 1];
    float st, ct, sp, cp;
    sincosf(th, &st, &ct);
    sincosf(ph, &sp, &cp);
    const float Y00 = 0.28209479177387814f;
    const float H3  = 0.4886025119029199f;
    const float H15 = 1.0925484305920792f;
    const float Q5  = 0.31539156525252005f;
    const float Q15 = 0.5462742152960396f;
    float Y[9];
    Y[0] = Y00;
    Y[1] = H3 * st * sp;
    Y[2] = H3 * ct;
    Y[3] = H3 * st * cp;
    Y[4] = H15 * (st * cp) * (st * sp);
    Y[5] = H15 * (st * sp) * ct;
    Y[6] = Q5 * (3.f * ct * ct - 1.f);
    Y[7] = H15 * (st * cp) * ct;
    Y[8] = Q15 * ((st * cp) * (st * cp) - (st * sp) * (st * sp));

    // ---- gather: 2 corners along z for this (sample, dx, dy) ----
    const float* pp = pos + ((size_t)r * NS + s) * 3;
    const float x = pp[0], y = pp[1], z = pp[2];
    const float fx0 = floorf(x), fy0 = floorf(y), fz0 = floorf(z);
    const float fx = x - fx0, fy = y - fy0, fz = z - fz0;
    const int jx  = min(max((int)fx0 + dx, 0), GDIM - 1);
    const int jy  = min(max((int)fy0 + dy, 0), GDIM - 1);
    const int jz0 = min(max((int)fz0,      0), GDIM - 1);
    const int jz1 = min(max((int)fz0 + 1,  0), GDIM - 1);

    const float wxy = (dx ? fx : 1.f - fx) * (dy ? fy : 1.f - fy);
    const float wz0 = wxy * (1.f - fz);
    const float wz1 = wxy * fz;

    const float4* g0 = (const float4*)(grid + (((size_t)jx * GDIM + jy) * GDIM + jz0) * VD);
    const float4* g1 = (const float4*)(grid + (((size_t)jx * GDIM + jy) * GDIM + jz1) * VD);

    float f0[28], f1[28];
#pragma unroll
    for (int j = 0; j < 7; ++j) ((float4*)f0)[j] = g0[j];   // 14 independent loads,
#pragma unroll
    for (int j = 0; j < 7; ++j) ((float4*)f1)[j] = g1[j];   // one latency exposure

    float psig = wz0 * f0[0] + wz1 * f1[0];
    float d0r = 0.f, d0g = 0.f, d0b = 0.f;
    float d1r = 0.f, d1g = 0.f, d1b = 0.f;
#pragma unroll
    for (int n = 0; n < 9; ++n) {
        d0r += f0[1 + n]  * Y[n];
        d0g += f0[10 + n] * Y[n];
        d0b += f0[19 + n] * Y[n];
        d1r += f1[1 + n]  * Y[n];
        d1g += f1[10 + n] * Y[n];
        d1b += f1[19 + n] * Y[n];
    }
    float pr = wz0 * d0r + wz1 * d1r;
    float pg = wz0 * d0g + wz1 * d1g;
    float pb = wz0 * d0b + wz1 * d1b;

    // ---- quad butterfly: all 4 lanes of the quad get full-sample sums ----
#pragma unroll
    for (int o = 1; o <= 2; o <<= 1) {
        psig += __shfl_xor(psig, (unsigned)o, 64);
        pr   += __shfl_xor(pr,   (unsigned)o, 64);
        pg   += __shfl_xor(pg,   (unsigned)o, 64);
        pb   += __shfl_xor(pb,   (unsigned)o, 64);
    }

    // ---- att + inclusive cumsum over samples ----
    const float d   = dist[(size_t)r * NS + s];
    const float att = expf(-psig * d);

    // quad-granular inclusive scan within wave (16 samples/wave):
    // values are quad-replicated, so offsets 4,8,16,32 pick one lane per quad.
    float t = att;
#pragma unroll
    for (int o = 4; o < 64; o <<= 1) {
        const float v = __shfl_up(t, (unsigned)o, 64);
        if (lane >= o) t += v;
    }

    __shared__ float wave_sum[8];
    __shared__ float fin[8][3];
    if (lane == 63) wave_sum[wv] = t;          // wave total (last sample inclusive)
    __syncthreads();
    float carry = 0.f;
#pragma unroll
    for (int w = 0; w < 8; ++w) carry += (w < wv) ? wave_sum[w] : 0.f;

    const float trans  = t + carry;
    const float weight = trans * (1.f - att);

    // ---- weighted RGB: one contribution per quad, butterfly over quads ----
    const float m = (p == 0) ? weight : 0.f;
    float a0 = m * pr, a1 = m * pg, a2 = m * pb;
#pragma unroll
    for (int o = 4; o < 64; o <<= 1) {
        a0 += __shfl_xor(a0, (unsigned)o, 64);
        a1 += __shfl_xor(a1, (unsigned)o, 64);
        a2 += __shfl_xor(a2, (unsigned)o, 64);
    }
    if (lane == 0) { fin[wv][0] = a0; fin[wv][1] = a1; fin[wv][2] = a2; }
    __syncthreads();

    if (tid < 3) {
        float acc = 0.f;
#pragma unroll
        for (int w = 0; w < 8; ++w) acc += fin[w][tid];
        out[(size_t)r * 3 + tid] = acc;
    }
}

extern "C" void kernel_launch(void* const* d_in, const int* in_sizes, int n_in,
                              void* d_out, int out_size, void* d_ws, size_t ws_size,
                              hipStream_t stream) {
    const float* grid = (const float*)d_in[0];
    const float* pos  = (const float*)d_in[1];
    const float* dst  = (const float*)d_in[2];
    const float* ang  = (const float*)d_in[3];
    float* out = (float*)d_out;

    const int R = in_sizes[3] / 2;   // 2048 rays
    plenoxel_kernel<<<R, 512, 0, stream>>>(grid, pos, dst, ang, out);
}

// Round 4
// 322.468 us; speedup vs baseline: 1.1488x; 1.1488x over previous
//
#include <hip/hip_runtime.h>

#define GDIM 128
#define NS   128
#define VD   28

// Quad-cooperative gather: quad = one sample; lane p of the quad loads the
// 16B slice at byte offset 64*i + 16*p of each 224B z-pair column (4 columns,
// one per (dx,dy)). Adjacent lanes hit the same cache line -> coalesced.
// Channel->SH mapping is lane-dependent; resolved at compile time per P.
template<int P>
__device__ __forceinline__ void accum_col(const float4* L, float wz0, float wz1,
                                          const float* Y,
                                          float& sg, float& rr, float& gg, float& bb)
{
#pragma unroll
    for (int i = 0; i < 4; ++i) {
        const float4 v = L[i];
#pragma unroll
        for (int k = 0; k < 4; ++k) {
            const int c = 16 * i + 4 * P + k;      // column element index 0..63
            if (c < 56) {                          // 56 floats = 2 corners x 28
                const float f = (k == 0) ? v.x : (k == 1) ? v.y : (k == 2) ? v.z : v.w;
                const float w = (c < 28) ? wz0 : wz1;
                const int  ch = (c < 28) ? c : (c - 28);
                if (ch == 0)       sg += w * f;
                else if (ch < 10)  rr += (w * Y[ch - 1])  * f;
                else if (ch < 19)  gg += (w * Y[ch - 10]) * f;
                else               bb += (w * Y[ch - 19]) * f;
            }
        }
    }
}

__global__ __launch_bounds__(512, 4) void plenoxel_kernel(
    const float* __restrict__ grid,
    const float* __restrict__ pos,
    const float* __restrict__ dist,
    const float* __restrict__ ang,
    float* __restrict__ out)
{
    const int r    = blockIdx.x;
    const int tid  = threadIdx.x;        // 0..511
    const int s    = tid >> 2;           // sample 0..127
    const int p    = tid & 3;            // quad slice 0..3
    const int lane = tid & 63;
    const int wv   = tid >> 6;           // wave 0..7 (16 samples each)

    // ---- SH basis ----
    const float th = ang[2 * r + 0];
    const float ph = ang[2 * r + 1];
    float st, ct, sp, cp;
    sincosf(th, &st, &ct);
    sincosf(ph, &sp, &cp);
    const float Y00 = 0.28209479177387814f;
    const float H3  = 0.4886025119029199f;
    const float H15 = 1.0925484305920792f;
    const float Q5  = 0.31539156525252005f;
    const float Q15 = 0.5462742152960396f;
    float Y[9];
    Y[0] = Y00;
    Y[1] = H3 * st * sp;
    Y[2] = H3 * ct;
    Y[3] = H3 * st * cp;
    Y[4] = H15 * (st * cp) * (st * sp);
    Y[5] = H15 * (st * sp) * ct;
    Y[6] = Q5 * (3.f * ct * ct - 1.f);
    Y[7] = H15 * (st * cp) * ct;
    Y[8] = Q15 * ((st * cp) * (st * cp) - (st * sp) * (st * sp));

    // ---- position / weights (whole quad reads same sample) ----
    const float* pp = pos + ((size_t)r * NS + s) * 3;
    const float x = pp[0], y = pp[1], z = pp[2];
    const float fx0 = floorf(x), fy0 = floorf(y), fz0 = floorf(z);
    const float fx = x - fx0, fy = y - fy0, fz = z - fz0;
    const int jx0 = min(max((int)fx0,     0), GDIM - 1);
    const int jx1 = min(max((int)fx0 + 1, 0), GDIM - 1);
    const int jy0 = min(max((int)fy0,     0), GDIM - 1);
    const int jy1 = min(max((int)fy0 + 1, 0), GDIM - 1);
    const int jz0 = min(max((int)fz0,     0), GDIM - 2);  // z-pair contiguous

    const float* col[4];
    col[0] = grid + (((size_t)jx0 * GDIM + jy0) * GDIM + jz0) * VD;
    col[1] = grid + (((size_t)jx0 * GDIM + jy1) * GDIM + jz0) * VD;
    col[2] = grid + (((size_t)jx1 * GDIM + jy0) * GDIM + jz0) * VD;
    col[3] = grid + (((size_t)jx1 * GDIM + jy1) * GDIM + jz0) * VD;
    const float wxy[4] = {(1.f - fx) * (1.f - fy), (1.f - fx) * fy,
                          fx * (1.f - fy),         fx * fy};
    float wza[4], wzb[4];
#pragma unroll
    for (int q = 0; q < 4; ++q) { wza[q] = wxy[q] * (1.f - fz); wzb[q] = wxy[q] * fz; }

    // ---- 16 coalesced loads (all issued before any use) ----
    float4 L[4][4];
#pragma unroll
    for (int q = 0; q < 4; ++q)
#pragma unroll
        for (int i = 0; i < 4; ++i)
            L[q][i] = *(const float4*)(col[q] + 16 * i + 4 * p);

    float sg = 0.f, rr = 0.f, gg = 0.f, bb = 0.f;
    switch (p) {
    case 0:
#pragma unroll
        for (int q = 0; q < 4; ++q) accum_col<0>(L[q], wza[q], wzb[q], Y, sg, rr, gg, bb);
        break;
    case 1:
#pragma unroll
        for (int q = 0; q < 4; ++q) accum_col<1>(L[q], wza[q], wzb[q], Y, sg, rr, gg, bb);
        break;
    case 2:
#pragma unroll
        for (int q = 0; q < 4; ++q) accum_col<2>(L[q], wza[q], wzb[q], Y, sg, rr, gg, bb);
        break;
    default:
#pragma unroll
        for (int q = 0; q < 4; ++q) accum_col<3>(L[q], wza[q], wzb[q], Y, sg, rr, gg, bb);
        break;
    }

    // ---- quad butterfly: all lanes get the full trilinear result ----
#pragma unroll
    for (int o = 1; o <= 2; o <<= 1) {
        sg += __shfl_xor(sg, (unsigned)o, 64);
        rr += __shfl_xor(rr, (unsigned)o, 64);
        gg += __shfl_xor(gg, (unsigned)o, 64);
        bb += __shfl_xor(bb, (unsigned)o, 64);
    }

    // ---- att + inclusive cumsum over samples (quad-granular scan) ----
    const float d   = dist[(size_t)r * NS + s];
    const float att = expf(-sg * d);

    float t = att;
#pragma unroll
    for (int o = 4; o < 64; o <<= 1) {
        const float v = __shfl_up(t, (unsigned)o, 64);
        if (lane >= o) t += v;
    }

    __shared__ float wave_sum[8];
    __shared__ float fin[8][3];
    if (lane == 63) wave_sum[wv] = t;
    __syncthreads();
    float carry = 0.f;
#pragma unroll
    for (int w = 0; w < 8; ++w) carry += (w < wv) ? wave_sum[w] : 0.f;

    const float trans  = t + carry;
    const float weight = trans * (1.f - att);

    // ---- weighted RGB: one contribution per quad, butterfly over quads ----
    const float m = (p == 0) ? weight : 0.f;
    float a0 = m * rr, a1 = m * gg, a2 = m * bb;
#pragma unroll
    for (int o = 4; o < 64; o <<= 1) {
        a0 += __shfl_xor(a0, (unsigned)o, 64);
        a1 += __shfl_xor(a1, (unsigned)o, 64);
        a2 += __shfl_xor(a2, (unsigned)o, 64);
    }
    if (lane == 0) { fin[wv][0] = a0; fin[wv][1] = a1; fin[wv][2] = a2; }
    __syncthreads();

    if (tid < 3) {
        float acc = 0.f;
#pragma unroll
        for (int w = 0; w < 8; ++w) acc += fin[w][tid];
        out[(size_t)r * 3 + tid] = acc;
    }
}

extern "C" void kernel_launch(void* const* d_in, const int* in_sizes, int n_in,
                              void* d_out, int out_size, void* d_ws, size_t ws_size,
                              hipStream_t stream) {
    const float* grid = (const float*)d_in[0];
    const float* pos  = (const float*)d_in[1];
    const float* dst  = (const float*)d_in[2];
    const float* ang  = (const float*)d_in[3];
    float* out = (float*)d_out;

    const int R = in_sizes[3] / 2;   // 2048 rays
    plenoxel_kernel<<<R, 512, 0, stream>>>(grid, pos, dst, ang, out);
}